// Round 1
// baseline (376.469 us; speedup 1.0000x reference)
//
#include <hip/hip_runtime.h>

// EdgeLoss: weighted BCE-with-logits mean over 32x1x768x1024 fp32 tensors.
// result = (neg_num * S_pos + pos_num * S_neg) / (pos_num + neg_num) / n
// where S_pos = sum over t==1 of bce(x,1), S_neg = sum over t==0 of bce(x,0),
// bce(x,t) = max(x,0) - x*t + log1p(exp(-|x|)).

#define WS_POS_CNT 0
#define WS_NEG_CNT 1
#define WS_SUM_POS 2
#define WS_SUM_NEG 3

__global__ __launch_bounds__(256) void edge_loss_reduce(
    const float* __restrict__ x, const float* __restrict__ t,
    double* __restrict__ ws, long long n) {
  long long tid = (long long)blockIdx.x * blockDim.x + threadIdx.x;
  long long stride = (long long)gridDim.x * blockDim.x;
  long long n4 = n >> 2;

  float cp = 0.f, cn = 0.f, sp = 0.f, sn = 0.f;

  const float4* __restrict__ x4 = (const float4*)x;
  const float4* __restrict__ t4 = (const float4*)t;

  auto do_elem = [&](float xv, float tv) {
    float a = fabsf(xv);
    float spl = log1pf(__expf(-a));            // log1p(exp(-|x|)), exact-enough
    float common = fmaxf(xv, 0.f) + spl;       // bce for t==0; bce(t==1)=common-x
    if (tv == 1.0f) { cp += 1.f; sp += common - xv; }
    else if (tv == 0.0f) { cn += 1.f; sn += common; }
    // tv == 2 (ignore): weight 0, contributes nothing
  };

  for (long long i = tid; i < n4; i += stride) {
    float4 xv = x4[i];
    float4 tv = t4[i];
    do_elem(xv.x, tv.x);
    do_elem(xv.y, tv.y);
    do_elem(xv.z, tv.z);
    do_elem(xv.w, tv.w);
  }
  // scalar tail (n may not be a multiple of 4 in general)
  for (long long i = (n4 << 2) + tid; i < n; i += stride) {
    do_elem(x[i], t[i]);
  }

  // wave-64 shuffle reduction
  #pragma unroll
  for (int off = 32; off > 0; off >>= 1) {
    cp += __shfl_down(cp, off, 64);
    cn += __shfl_down(cn, off, 64);
    sp += __shfl_down(sp, off, 64);
    sn += __shfl_down(sn, off, 64);
  }

  __shared__ float s_cp[4], s_cn[4], s_sp[4], s_sn[4];
  int lane = threadIdx.x & 63;
  int wave = threadIdx.x >> 6;
  if (lane == 0) { s_cp[wave] = cp; s_cn[wave] = cn; s_sp[wave] = sp; s_sn[wave] = sn; }
  __syncthreads();
  if (threadIdx.x == 0) {
    float tcp = 0.f, tcn = 0.f, tsp = 0.f, tsn = 0.f;
    #pragma unroll
    for (int i = 0; i < 4; ++i) { tcp += s_cp[i]; tcn += s_cn[i]; tsp += s_sp[i]; tsn += s_sn[i]; }
    atomicAdd(&ws[WS_POS_CNT], (double)tcp);
    atomicAdd(&ws[WS_NEG_CNT], (double)tcn);
    atomicAdd(&ws[WS_SUM_POS], (double)tsp);
    atomicAdd(&ws[WS_SUM_NEG], (double)tsn);
  }
}

__global__ void edge_loss_finalize(const double* __restrict__ ws,
                                   float* __restrict__ out, double inv_n) {
  double pos = ws[WS_POS_CNT];
  double neg = ws[WS_NEG_CNT];
  double s = pos + neg;
  double res = (neg * ws[WS_SUM_POS] + pos * ws[WS_SUM_NEG]) / s * inv_n;
  out[0] = (float)res;
}

extern "C" void kernel_launch(void* const* d_in, const int* in_sizes, int n_in,
                              void* d_out, int out_size, void* d_ws, size_t ws_size,
                              hipStream_t stream) {
  const float* x = (const float*)d_in[0];
  const float* t = (const float*)d_in[1];
  long long n = (long long)in_sizes[0];
  double* ws = (double*)d_ws;

  hipMemsetAsync(ws, 0, 4 * sizeof(double), stream);

  const int block = 256;
  const int grid = 4096;  // 256 CUs * 16 blocks; ~6 float4 iters/thread at n=25.17M
  edge_loss_reduce<<<grid, block, 0, stream>>>(x, t, ws, n);
  edge_loss_finalize<<<1, 1, 0, stream>>>(ws, (float*)d_out, 1.0 / (double)n);
}